// Round 9
// baseline (338.521 us; speedup 1.0000x reference)
//
#include <hip/hip_runtime.h>
#include <hip/hip_bf16.h>

typedef __attribute__((ext_vector_type(8)))  __bf16 bf16x8;
typedef __attribute__((ext_vector_type(4)))  float  f32x4;

// ---------------------------------------------------------------------------
// Merged preprocessing: blocks [0, wBlocks) convert W fp32->bf16 (grid-stride);
// blocks [wBlocks, ...) compute mid = x@A^T (4 rows/block) + convert x->bf16.
// ---------------------------------------------------------------------------
__global__ __launch_bounds__(256) void preproc(
    const float* __restrict__ x, const float* __restrict__ A,
    const float* __restrict__ Wf,
    float* __restrict__ mid, __bf16* __restrict__ Xb, __bf16* __restrict__ Wbb,
    int K, int M, long nW8, int wBlocks)
{
    int tid = threadIdx.x;
    if ((int)blockIdx.x < wBlocks) {
        long i = (long)blockIdx.x * 256 + tid;
        long stride = (long)wBlocks * 256;
        for (; i < nW8; i += stride) {
            const f32x4* p = (const f32x4*)(Wf + i * 8);
            f32x4 a = p[0], b = p[1];
            bf16x8 o;
            o[0] = (__bf16)a[0]; o[1] = (__bf16)a[1];
            o[2] = (__bf16)a[2]; o[3] = (__bf16)a[3];
            o[4] = (__bf16)b[0]; o[5] = (__bf16)b[1];
            o[6] = (__bf16)b[2]; o[7] = (__bf16)b[3];
            *(bf16x8*)(Wbb + i * 8) = o;
        }
        return;
    }

    int m0 = ((int)blockIdx.x - wBlocks) * 4;
    float acc[4][16];
#pragma unroll
    for (int row = 0; row < 4; ++row)
#pragma unroll
        for (int r = 0; r < 16; ++r) acc[row][r] = 0.f;

    int iters = K / 2048;
    for (int it = 0; it < iters; ++it) {
        int k = it * 2048 + tid * 8;
        f32x4 xv[4][2];
#pragma unroll
        for (int row = 0; row < 4; ++row) {
            if (m0 + row < M) {
                const float* xr = x + (size_t)(m0 + row) * K;
                xv[row][0] = *(const f32x4*)(xr + k);
                xv[row][1] = *(const f32x4*)(xr + k + 4);
                bf16x8 o;
                o[0] = (__bf16)xv[row][0][0]; o[1] = (__bf16)xv[row][0][1];
                o[2] = (__bf16)xv[row][0][2]; o[3] = (__bf16)xv[row][0][3];
                o[4] = (__bf16)xv[row][1][0]; o[5] = (__bf16)xv[row][1][1];
                o[6] = (__bf16)xv[row][1][2]; o[7] = (__bf16)xv[row][1][3];
                *(bf16x8*)(Xb + (size_t)(m0 + row) * K + k) = o;
            } else {
                f32x4 z = {0.f,0.f,0.f,0.f};
                xv[row][0] = z; xv[row][1] = z;
            }
        }
#pragma unroll
        for (int r = 0; r < 16; ++r) {
            const f32x4* ap = (const f32x4*)(A + (size_t)r * K + k);
            f32x4 a0 = ap[0], a1 = ap[1];
#pragma unroll
            for (int row = 0; row < 4; ++row) {
                acc[row][r] += xv[row][0][0]*a0[0] + xv[row][0][1]*a0[1]
                             + xv[row][0][2]*a0[2] + xv[row][0][3]*a0[3]
                             + xv[row][1][0]*a1[0] + xv[row][1][1]*a1[1]
                             + xv[row][1][2]*a1[2] + xv[row][1][3]*a1[3];
            }
        }
    }

#pragma unroll
    for (int row = 0; row < 4; ++row)
#pragma unroll
        for (int r = 0; r < 16; ++r)
#pragma unroll
            for (int off = 32; off > 0; off >>= 1)
                acc[row][r] += __shfl_down(acc[row][r], off, 64);

    __shared__ float red[4][4][16];
    int lane = tid & 63, w = tid >> 6;
    if (lane == 0) {
#pragma unroll
        for (int row = 0; row < 4; ++row)
#pragma unroll
            for (int r = 0; r < 16; ++r) red[w][row][r] = acc[row][r];
    }
    __syncthreads();
    if (tid < 64) {
        int row = tid >> 4, r = tid & 15;
        if (m0 + row < M) {
            float s = red[0][row][r] + red[1][row][r]
                    + red[2][row][r] + red[3][row][r];
            mid[(size_t)(m0 + row) * 16 + r] = s;
        }
    }
}

// standalone mid (fallback path)
__global__ __launch_bounds__(256) void mid_only(
    const float* __restrict__ x, const float* __restrict__ A,
    float* __restrict__ mid, int K, int M)
{
    int tid = threadIdx.x;
    int m0 = blockIdx.x * 4;
    float acc[4][16];
#pragma unroll
    for (int row = 0; row < 4; ++row)
#pragma unroll
        for (int r = 0; r < 16; ++r) acc[row][r] = 0.f;
    int iters = K / 2048;
    for (int it = 0; it < iters; ++it) {
        int k = it * 2048 + tid * 8;
        f32x4 xv[4][2];
#pragma unroll
        for (int row = 0; row < 4; ++row) {
            if (m0 + row < M) {
                const float* xr = x + (size_t)(m0 + row) * K;
                xv[row][0] = *(const f32x4*)(xr + k);
                xv[row][1] = *(const f32x4*)(xr + k + 4);
            } else {
                f32x4 z = {0.f,0.f,0.f,0.f};
                xv[row][0] = z; xv[row][1] = z;
            }
        }
#pragma unroll
        for (int r = 0; r < 16; ++r) {
            const f32x4* ap = (const f32x4*)(A + (size_t)r * K + k);
            f32x4 a0 = ap[0], a1 = ap[1];
#pragma unroll
            for (int row = 0; row < 4; ++row) {
                acc[row][r] += xv[row][0][0]*a0[0] + xv[row][0][1]*a0[1]
                             + xv[row][0][2]*a0[2] + xv[row][0][3]*a0[3]
                             + xv[row][1][0]*a1[0] + xv[row][1][1]*a1[1]
                             + xv[row][1][2]*a1[2] + xv[row][1][3]*a1[3];
            }
        }
    }
#pragma unroll
    for (int row = 0; row < 4; ++row)
#pragma unroll
        for (int r = 0; r < 16; ++r)
#pragma unroll
            for (int off = 32; off > 0; off >>= 1)
                acc[row][r] += __shfl_down(acc[row][r], off, 64);
    __shared__ float red[4][4][16];
    int lane = tid & 63, w = tid >> 6;
    if (lane == 0) {
#pragma unroll
        for (int row = 0; row < 4; ++row)
#pragma unroll
            for (int r = 0; r < 16; ++r) red[w][row][r] = acc[row][r];
    }
    __syncthreads();
    if (tid < 64) {
        int row = tid >> 4, r = tid & 15;
        if (m0 + row < M) {
            float s = red[0][row][r] + red[1][row][r]
                    + red[2][row][r] + red[3][row][r];
            mid[(size_t)(m0 + row) * 16 + r] = s;
        }
    }
}

// ---------------------------------------------------------------------------
// 256x256-tile bf16 MFMA NT-GEMM, 512 threads (8 waves 2x4), BK=32 slabs,
// 4 LDS buffers, staging 2 slabs ahead, counted vmcnt(4)/slab.
// R9: m201 phase ORDERING -- fragments are read at the TOP of the phase
// (before the barrier, in the shadow of the previous phase's barrier
// convergence) and consumed in the SAME phase after lgkmcnt(0)+fence:
//   PhA(t): [read B0-3,A0-3(t)][stage A(t+2)][BAR][lgkm0][fence][16 MFMA][BAR]
//   PhB(t): [read A4-7(t)][stage B(t+2)][vmcnt(4)][BAR][lgkm0][fence][16 MFMA][BAR]
// This is the one structural difference vs R5-R8 (all 1190-1294 cy/phase);
// m201 with this ordering measures 824 cy/phase on identical per-phase work.
// Race discipline identical to R6 (proven): VMW(4) pre-barrier at PhB(t-1)
// certifies slab t before PhA(t) reads; write-after-read distance 2 slabs.
// ---------------------------------------------------------------------------
#define GL16(g, l) __builtin_amdgcn_global_load_lds( \
    (const __attribute__((address_space(1))) void*)(g), \
    (__attribute__((address_space(3))) void*)(l), 16, 0, 0)

#define DSR(dst, addr, IMM) \
    asm volatile("ds_read_b128 %0, %1 offset:" IMM : "=v"(dst) : "v"(addr))

#define BAR()   __builtin_amdgcn_s_barrier()
#define LGKM0() asm volatile("s_waitcnt lgkmcnt(0)" ::: )
#define FENCE() __builtin_amdgcn_sched_barrier(0)
#define VMW(n)  asm volatile("s_waitcnt vmcnt(" #n ")" ::: "memory")

__global__ __launch_bounds__(512, 2) void gemm256(
    const __bf16* __restrict__ Xb,   // [M][K]
    const __bf16* __restrict__ Wb,   // [N][K]
    const float*  __restrict__ mid,  // [M][16]
    const float*  __restrict__ Bl,   // [N][16]
    float* __restrict__ out,         // [M][N]
    int M, int N, int K)
{
    __shared__ __bf16 As[4][256 * 32];   // 4 x 16 KiB
    __shared__ __bf16 Bs[4][256 * 32];   // 4 x 16 KiB  -> 128 KiB total

    const int NT = K >> 5;               // BK = 32

    int nbx = N >> 8, nby = M >> 8, nwg = nbx * nby;
    int bid = blockIdx.x, swz = bid;
    if ((nwg & 7) == 0) { int cpx = nwg >> 3; swz = (bid & 7) * cpx + (bid >> 3); }
    int by = swz / nbx, bx = swz % nbx;
    int m0 = by << 8, n0 = bx << 8;

    int tid = threadIdx.x;
    int lane = tid & 63;
    int w = tid >> 6;            // wave 0..7
    int wm = w >> 2, wn = w & 3; // 2 x 4 wave grid; wave tile = 128 x 64

    // ---- staging source (pre-swizzled global chunk, linear LDS dest) ----
    int q0 = tid >> 2;
    int c0 = tid & 3;
    int csrc = c0 ^ ((q0 >> 1) & 3);
    const __bf16* sA0 = Xb + (size_t)(m0 + q0) * K + csrc * 8;
    const __bf16* sA1 = sA0 + (size_t)128 * K;
    const __bf16* sB0 = Wb + (size_t)(n0 + q0) * K + csrc * 8;
    const __bf16* sB1 = sB0 + (size_t)128 * K;
    unsigned ldsw = (unsigned)w * 1024;

#define STAGE_A(t, b) do { size_t ko = (size_t)(t) * 32; \
    GL16(sA0 + ko, (char*)As[b] + ldsw); \
    GL16(sA1 + ko, (char*)As[b] + 8192 + ldsw); } while (0)
#define STAGE_B(t, b) do { size_t ko = (size_t)(t) * 32; \
    GL16(sB0 + ko, (char*)Bs[b] + ldsw); \
    GL16(sB1 + ko, (char*)Bs[b] + 8192 + ldsw); } while (0)

    // ---- swizzled ds_read byte offsets (16x16 pattern, 0-conflict proven) --
    int chunkSwz = (lane >> 4) ^ ((lane >> 1) & 3);
    unsigned aoff = (unsigned)((wm * 128 + (lane & 15)) * 64 + chunkSwz * 16);
    unsigned boff = (unsigned)((wn * 64  + (lane & 15)) * 64 + chunkSwz * 16);
    unsigned a_addr = (unsigned)(size_t)(__attribute__((address_space(3))) __bf16*)&As[0][0] + aoff;
    unsigned b_addr = (unsigned)(size_t)(__attribute__((address_space(3))) __bf16*)&Bs[0][0] + boff;

    // ---- acc init = LoRA contribution: mfma([mid|0], [2*Bl|0]) over K=32 ----
    f32x4 acc[8][4];
    {
        int kh = lane >> 4;
        bf16x8 bI[4];
#pragma unroll
        for (int j = 0; j < 4; ++j) {
            bf16x8 v = {};
            if (kh < 2) {
                int col = n0 + wn * 64 + j * 16 + (lane & 15);
                const f32x4* p = (const f32x4*)(Bl + (size_t)col * 16 + kh * 8);
                f32x4 v0 = p[0], v1 = p[1];
                v[0] = (__bf16)(2.0f * v0[0]); v[1] = (__bf16)(2.0f * v0[1]);
                v[2] = (__bf16)(2.0f * v0[2]); v[3] = (__bf16)(2.0f * v0[3]);
                v[4] = (__bf16)(2.0f * v1[0]); v[5] = (__bf16)(2.0f * v1[1]);
                v[6] = (__bf16)(2.0f * v1[2]); v[7] = (__bf16)(2.0f * v1[3]);
            }
            bI[j] = v;
        }
#pragma unroll
        for (int i = 0; i < 8; ++i) {
            bf16x8 aI = {};
            if (kh < 2) {
                int row = m0 + wm * 128 + i * 16 + (lane & 15);
                const f32x4* p = (const f32x4*)(mid + (size_t)row * 16 + kh * 8);
                f32x4 v0 = p[0], v1 = p[1];
                aI[0] = (__bf16)v0[0]; aI[1] = (__bf16)v0[1];
                aI[2] = (__bf16)v0[2]; aI[3] = (__bf16)v0[3];
                aI[4] = (__bf16)v1[0]; aI[5] = (__bf16)v1[1];
                aI[6] = (__bf16)v1[2]; aI[7] = (__bf16)v1[3];
            }
            f32x4 z = {0.f, 0.f, 0.f, 0.f};
#pragma unroll
            for (int j = 0; j < 4; ++j)
                acc[i][j] = __builtin_amdgcn_mfma_f32_16x16x32_bf16(aI, bI[j], z, 0, 0, 0);
        }
    }

    // ---- prologue: stage slabs 0,1; certify slab 0; publish ----
    STAGE_A(0, 0); STAGE_B(0, 0);
    STAGE_A(1, 1); STAGE_B(1, 1);
    VMW(4);                  // slab 0 landed (own loads); slab 1 in flight
    BAR();                   // publish to all waves

    bf16x8 af0, af1, af2, af3, af4, af5, af6, af7, bf0, bf1, bf2, bf3;

    // ---- main K loop: one slab per iteration, 2 phases (m201 ordering) ----
    for (int t = 0; t < NT; ++t) {
        unsigned aT = a_addr + ((unsigned)(t & 3) << 14);
        unsigned bT = b_addr + ((unsigned)(t & 3) << 14);
        bool p2 = (t + 2) < NT;

        // ===== PhA(t): read B0-3 + A0-3; stage A(t+2); BAR; MFMA Q1 =====
        DSR(bf0, bT, "0");    DSR(bf1, bT, "1024");
        DSR(bf2, bT, "2048"); DSR(bf3, bT, "3072");
        DSR(af0, aT, "0");    DSR(af1, aT, "1024");
        DSR(af2, aT, "2048"); DSR(af3, aT, "3072");
        if (p2) STAGE_A(t + 2, (t + 2) & 3);
        BAR();
        LGKM0();
        FENCE();   // rule #18: MFMA consumes just-waited asm ds_read results
        __builtin_amdgcn_s_setprio(1);
        acc[0][0] = __builtin_amdgcn_mfma_f32_16x16x32_bf16(af0, bf0, acc[0][0], 0, 0, 0);
        acc[0][1] = __builtin_amdgcn_mfma_f32_16x16x32_bf16(af0, bf1, acc[0][1], 0, 0, 0);
        acc[0][2] = __builtin_amdgcn_mfma_f32_16x16x32_bf16(af0, bf2, acc[0][2], 0, 0, 0);
        acc[0][3] = __builtin_amdgcn_mfma_f32_16x16x32_bf16(af0, bf3, acc[0][3], 0, 0, 0);
        acc[1][0] = __builtin_amdgcn_mfma_f32_16x16x32_bf16(af1, bf0, acc[1][0], 0, 0, 0);
        acc[1][1] = __builtin_amdgcn_mfma_f32_16x16x32_bf16(af1, bf1, acc[1][1], 0, 0, 0);
        acc[1][2] = __builtin_amdgcn_mfma_f32_16x16x32_bf16(af1, bf2, acc[1][2], 0, 0, 0);
        acc[1][3] = __builtin_amdgcn_mfma_f32_16x16x32_bf16(af1, bf3, acc[1][3], 0, 0, 0);
        acc[2][0] = __builtin_amdgcn_mfma_f32_16x16x32_bf16(af2, bf0, acc[2][0], 0, 0, 0);
        acc[2][1] = __builtin_amdgcn_mfma_f32_16x16x32_bf16(af2, bf1, acc[2][1], 0, 0, 0);
        acc[2][2] = __builtin_amdgcn_mfma_f32_16x16x32_bf16(af2, bf2, acc[2][2], 0, 0, 0);
        acc[2][3] = __builtin_amdgcn_mfma_f32_16x16x32_bf16(af2, bf3, acc[2][3], 0, 0, 0);
        acc[3][0] = __builtin_amdgcn_mfma_f32_16x16x32_bf16(af3, bf0, acc[3][0], 0, 0, 0);
        acc[3][1] = __builtin_amdgcn_mfma_f32_16x16x32_bf16(af3, bf1, acc[3][1], 0, 0, 0);
        acc[3][2] = __builtin_amdgcn_mfma_f32_16x16x32_bf16(af3, bf2, acc[3][2], 0, 0, 0);
        acc[3][3] = __builtin_amdgcn_mfma_f32_16x16x32_bf16(af3, bf3, acc[3][3], 0, 0, 0);
        __builtin_amdgcn_s_setprio(0);
        BAR();

        // ===== PhB(t): read A4-7; stage B(t+2); vmcnt; BAR; MFMA Q2 =====
        DSR(af4, aT, "4096"); DSR(af5, aT, "5120");
        DSR(af6, aT, "6144"); DSR(af7, aT, "7168");
        if (p2) {
            STAGE_B(t + 2, (t + 2) & 3);
            VMW(4);          // in flight: A(t+2),B(t+2) -> slab t+1 landed
        } else {
            VMW(0);
        }
        BAR();
        LGKM0();
        FENCE();
        __builtin_amdgcn_s_setprio(1);
        acc[4][0] = __builtin_amdgcn_mfma_f32_16x16x32_bf16(af4, bf0, acc[4][0], 0, 0, 0);
        acc[4][1] = __builtin_amdgcn_mfma_f32_16x16x32_bf16(af4, bf1, acc[4][1], 0, 0, 0);
        acc[4][2] = __builtin_amdgcn_mfma_f32_16x16x32_bf16(af4, bf2, acc[4][2], 0, 0, 0);
        acc[4][3] = __builtin_amdgcn_mfma_f32_16x16x32_bf16(af4, bf3, acc[4][3], 0, 0, 0);
        acc[5][0] = __builtin_amdgcn_mfma_f32_16x16x32_bf16(af5, bf0, acc[5][0], 0, 0, 0);
        acc[5][1] = __builtin_amdgcn_mfma_f32_16x16x32_bf16(af5, bf1, acc[5][1], 0, 0, 0);
        acc[5][2] = __builtin_amdgcn_mfma_f32_16x16x32_bf16(af5, bf2, acc[5][2], 0, 0, 0);
        acc[5][3] = __builtin_amdgcn_mfma_f32_16x16x32_bf16(af5, bf3, acc[5][3], 0, 0, 0);
        acc[6][0] = __builtin_amdgcn_mfma_f32_16x16x32_bf16(af6, bf0, acc[6][0], 0, 0, 0);
        acc[6][1] = __builtin_amdgcn_mfma_f32_16x16x32_bf16(af6, bf1, acc[6][1], 0, 0, 0);
        acc[6][2] = __builtin_amdgcn_mfma_f32_16x16x32_bf16(af6, bf2, acc[6][2], 0, 0, 0);
        acc[6][3] = __builtin_amdgcn_mfma_f32_16x16x32_bf16(af6, bf3, acc[6][3], 0, 0, 0);
        acc[7][0] = __builtin_amdgcn_mfma_f32_16x16x32_bf16(af7, bf0, acc[7][0], 0, 0, 0);
        acc[7][1] = __builtin_amdgcn_mfma_f32_16x16x32_bf16(af7, bf1, acc[7][1], 0, 0, 0);
        acc[7][2] = __builtin_amdgcn_mfma_f32_16x16x32_bf16(af7, bf2, acc[7][2], 0, 0, 0);
        acc[7][3] = __builtin_amdgcn_mfma_f32_16x16x32_bf16(af7, bf3, acc[7][3], 0, 0, 0);
        __builtin_amdgcn_s_setprio(0);
        BAR();
    }

    // ---- epilogue: pure f32 stores (LoRA already in acc) ----
#pragma unroll
    for (int i = 0; i < 8; ++i) {
        int rbase = m0 + wm * 128 + i * 16 + ((lane >> 4) << 2);
#pragma unroll
        for (int q = 0; q < 4; ++q) {
            float* orow = out + (size_t)(rbase + q) * N;
            int colb = n0 + wn * 64 + (lane & 15);
            orow[colb]      = acc[i][0][q];
            orow[colb + 16] = acc[i][1][q];
            orow[colb + 32] = acc[i][2][q];
            orow[colb + 48] = acc[i][3][q];
        }
    }
}

// ---------------------------------------------------------------------------
// Fallback fp32 GEMM (used only if workspace too small for bf16 buffers)
// ---------------------------------------------------------------------------
__global__ __launch_bounds__(256) void gemm_fb(
    const float* __restrict__ X, const float* __restrict__ W,
    const float* __restrict__ mid, const float* __restrict__ Bl,
    float* __restrict__ out, int M, int N, int K)
{
    __shared__ float As[64][16];
    __shared__ float Bs[64][16];
    int nbx = N / 64;
    int bx = blockIdx.x % nbx, by = blockIdx.x / nbx;
    int m0 = by * 64, n0 = bx * 64;
    int tid = threadIdx.x;
    int tr = tid >> 4, tc = tid & 15;

    float acc[4][4] = {};
    for (int kt = 0; kt < K; kt += 16) {
#pragma unroll
        for (int s = 0; s < 4; ++s) {
            int c = s * 256 + tid;
            int row = c >> 4, kk = c & 15;
            As[row][kk] = X[(size_t)(m0 + row) * K + kt + kk];
            Bs[row][kk] = W[(size_t)(n0 + row) * K + kt + kk];
        }
        __syncthreads();
#pragma unroll
        for (int kk = 0; kk < 16; ++kk) {
            float av[4], bv[4];
#pragma unroll
            for (int i = 0; i < 4; ++i) { av[i] = As[tr*4+i][kk]; bv[i] = Bs[tc*4+i][kk]; }
#pragma unroll
            for (int i = 0; i < 4; ++i)
#pragma unroll
                for (int j = 0; j < 4; ++j) acc[i][j] += av[i] * bv[j];
        }
        __syncthreads();
    }
#pragma unroll
    for (int i = 0; i < 4; ++i) {
        int row = m0 + tr * 4 + i;
#pragma unroll
        for (int j = 0; j < 4; ++j) {
            int col = n0 + tc * 4 + j;
            float s = 0.f;
#pragma unroll
            for (int r = 0; r < 16; ++r)
                s += mid[(size_t)row * 16 + r] * Bl[(size_t)col * 16 + r];
            out[(size_t)row * N + col] = acc[i][j] + 2.0f * s;
        }
    }
}

// ---------------------------------------------------------------------------
extern "C" void kernel_launch(void* const* d_in, const int* in_sizes, int n_in,
                              void* d_out, int out_size, void* d_ws, size_t ws_size,
                              hipStream_t stream)
{
    const float* x   = (const float*)d_in[0];
    const float* Wf  = (const float*)d_in[1];
    const float* A   = (const float*)d_in[2];
    const float* Bl  = (const float*)d_in[3];
    float* out = (float*)d_out;

    int D = in_sizes[2] / 16;            // A is [16, D]
    int O = in_sizes[3] / 16;            // B is [O, 16]
    long M = (long)in_sizes[0] / D;      // x is [M, D]
    int K = D, N = O;

    size_t xb_bytes  = (size_t)M * K * 2;
    size_t wb_bytes  = (size_t)N * K * 2;
    size_t mid_bytes = (size_t)M * 16 * 4;

    bool shapes_ok = (M % 256 == 0) && (N % 256 == 0) && (K % 2048 == 0)
                     && (K / 32 >= 8);

    int midBlocks = (int)((M + 3) / 4);

    if (shapes_ok && ws_size >= xb_bytes + wb_bytes + mid_bytes) {
        __bf16* Xb  = (__bf16*)d_ws;
        __bf16* Wbb = (__bf16*)((char*)d_ws + xb_bytes);
        float*  mid = (float*)((char*)d_ws + xb_bytes + wb_bytes);

        const int wBlocks = 1024;
        long nW8 = (long)N * K / 8;
        preproc<<<wBlocks + midBlocks, 256, 0, stream>>>(
            x, A, Wf, mid, Xb, Wbb, K, (int)M, nW8, wBlocks);
        int nwg = (int)(M / 256) * (N / 256);
        gemm256<<<nwg, 512, 0, stream>>>(Xb, Wbb, mid, Bl, out, (int)M, N, K);
    } else {
        float* mid = (float*)d_ws;
        mid_only<<<midBlocks, 256, 0, stream>>>(x, A, mid, K, (int)M);
        int nwg = (int)(M / 64) * (N / 64);
        gemm_fb<<<nwg, 256, 0, stream>>>(x, Wf, mid, Bl, out, (int)M, N, K);
    }
}

// Round 10
// 327.830 us; speedup vs baseline: 1.0326x; 1.0326x over previous
//
#include <hip/hip_runtime.h>
#include <hip/hip_bf16.h>

typedef __attribute__((ext_vector_type(8)))  __bf16 bf16x8;
typedef __attribute__((ext_vector_type(4)))  float  f32x4;

// ---------------------------------------------------------------------------
// Merged preprocessing: blocks [0, wBlocks) convert W fp32->bf16 (grid-stride);
// blocks [wBlocks, ...) compute mid = x@A^T (4 rows/block) + convert x->bf16.
// (R8/R9 component, ~50 us, at BW floor.)
// ---------------------------------------------------------------------------
__global__ __launch_bounds__(256) void preproc(
    const float* __restrict__ x, const float* __restrict__ A,
    const float* __restrict__ Wf,
    float* __restrict__ mid, __bf16* __restrict__ Xb, __bf16* __restrict__ Wbb,
    int K, int M, long nW8, int wBlocks)
{
    int tid = threadIdx.x;
    if ((int)blockIdx.x < wBlocks) {
        long i = (long)blockIdx.x * 256 + tid;
        long stride = (long)wBlocks * 256;
        for (; i < nW8; i += stride) {
            const f32x4* p = (const f32x4*)(Wf + i * 8);
            f32x4 a = p[0], b = p[1];
            bf16x8 o;
            o[0] = (__bf16)a[0]; o[1] = (__bf16)a[1];
            o[2] = (__bf16)a[2]; o[3] = (__bf16)a[3];
            o[4] = (__bf16)b[0]; o[5] = (__bf16)b[1];
            o[6] = (__bf16)b[2]; o[7] = (__bf16)b[3];
            *(bf16x8*)(Wbb + i * 8) = o;
        }
        return;
    }

    int m0 = ((int)blockIdx.x - wBlocks) * 4;
    float acc[4][16];
#pragma unroll
    for (int row = 0; row < 4; ++row)
#pragma unroll
        for (int r = 0; r < 16; ++r) acc[row][r] = 0.f;

    int iters = K / 2048;
    for (int it = 0; it < iters; ++it) {
        int k = it * 2048 + tid * 8;
        f32x4 xv[4][2];
#pragma unroll
        for (int row = 0; row < 4; ++row) {
            if (m0 + row < M) {
                const float* xr = x + (size_t)(m0 + row) * K;
                xv[row][0] = *(const f32x4*)(xr + k);
                xv[row][1] = *(const f32x4*)(xr + k + 4);
                bf16x8 o;
                o[0] = (__bf16)xv[row][0][0]; o[1] = (__bf16)xv[row][0][1];
                o[2] = (__bf16)xv[row][0][2]; o[3] = (__bf16)xv[row][0][3];
                o[4] = (__bf16)xv[row][1][0]; o[5] = (__bf16)xv[row][1][1];
                o[6] = (__bf16)xv[row][1][2]; o[7] = (__bf16)xv[row][1][3];
                *(bf16x8*)(Xb + (size_t)(m0 + row) * K + k) = o;
            } else {
                f32x4 z = {0.f,0.f,0.f,0.f};
                xv[row][0] = z; xv[row][1] = z;
            }
        }
#pragma unroll
        for (int r = 0; r < 16; ++r) {
            const f32x4* ap = (const f32x4*)(A + (size_t)r * K + k);
            f32x4 a0 = ap[0], a1 = ap[1];
#pragma unroll
            for (int row = 0; row < 4; ++row) {
                acc[row][r] += xv[row][0][0]*a0[0] + xv[row][0][1]*a0[1]
                             + xv[row][0][2]*a0[2] + xv[row][0][3]*a0[3]
                             + xv[row][1][0]*a1[0] + xv[row][1][1]*a1[1]
                             + xv[row][1][2]*a1[2] + xv[row][1][3]*a1[3];
            }
        }
    }

#pragma unroll
    for (int row = 0; row < 4; ++row)
#pragma unroll
        for (int r = 0; r < 16; ++r)
#pragma unroll
            for (int off = 32; off > 0; off >>= 1)
                acc[row][r] += __shfl_down(acc[row][r], off, 64);

    __shared__ float red[4][4][16];
    int lane = tid & 63, w = tid >> 6;
    if (lane == 0) {
#pragma unroll
        for (int row = 0; row < 4; ++row)
#pragma unroll
            for (int r = 0; r < 16; ++r) red[w][row][r] = acc[row][r];
    }
    __syncthreads();
    if (tid < 64) {
        int row = tid >> 4, r = tid & 15;
        if (m0 + row < M) {
            float s = red[0][row][r] + red[1][row][r]
                    + red[2][row][r] + red[3][row][r];
            mid[(size_t)(m0 + row) * 16 + r] = s;
        }
    }
}

// standalone mid (fallback path)
__global__ __launch_bounds__(256) void mid_only(
    const float* __restrict__ x, const float* __restrict__ A,
    float* __restrict__ mid, int K, int M)
{
    int tid = threadIdx.x;
    int m0 = blockIdx.x * 4;
    float acc[4][16];
#pragma unroll
    for (int row = 0; row < 4; ++row)
#pragma unroll
        for (int r = 0; r < 16; ++r) acc[row][r] = 0.f;
    int iters = K / 2048;
    for (int it = 0; it < iters; ++it) {
        int k = it * 2048 + tid * 8;
        f32x4 xv[4][2];
#pragma unroll
        for (int row = 0; row < 4; ++row) {
            if (m0 + row < M) {
                const float* xr = x + (size_t)(m0 + row) * K;
                xv[row][0] = *(const f32x4*)(xr + k);
                xv[row][1] = *(const f32x4*)(xr + k + 4);
            } else {
                f32x4 z = {0.f,0.f,0.f,0.f};
                xv[row][0] = z; xv[row][1] = z;
            }
        }
#pragma unroll
        for (int r = 0; r < 16; ++r) {
            const f32x4* ap = (const f32x4*)(A + (size_t)r * K + k);
            f32x4 a0 = ap[0], a1 = ap[1];
#pragma unroll
            for (int row = 0; row < 4; ++row) {
                acc[row][r] += xv[row][0][0]*a0[0] + xv[row][0][1]*a0[1]
                             + xv[row][0][2]*a0[2] + xv[row][0][3]*a0[3]
                             + xv[row][1][0]*a1[0] + xv[row][1][1]*a1[1]
                             + xv[row][1][2]*a1[2] + xv[row][1][3]*a1[3];
            }
        }
    }
#pragma unroll
    for (int row = 0; row < 4; ++row)
#pragma unroll
        for (int r = 0; r < 16; ++r)
#pragma unroll
            for (int off = 32; off > 0; off >>= 1)
                acc[row][r] += __shfl_down(acc[row][r], off, 64);
    __shared__ float red[4][4][16];
    int lane = tid & 63, w = tid >> 6;
    if (lane == 0) {
#pragma unroll
        for (int row = 0; row < 4; ++row)
#pragma unroll
            for (int r = 0; r < 16; ++r) red[w][row][r] = acc[row][r];
    }
    __syncthreads();
    if (tid < 64) {
        int row = tid >> 4, r = tid & 15;
        if (m0 + row < M) {
            float s = red[0][row][r] + red[1][row][r]
                    + red[2][row][r] + red[3][row][r];
            mid[(size_t)(m0 + row) * 16 + r] = s;
        }
    }
}

// ---------------------------------------------------------------------------
// R10 GEMM = byte-for-byte the R6 kernel (best measured: 254 us, MfmaUtil 49,
// 0 bank conflicts, 92->116 VGPR). 256x256 tile, 512 threads (8 waves 2x4),
// BK=32 slabs, 4 LDS buffers, staging 2 slabs ahead, counted vmcnt(4)/slab.
// Fragment reads = inline-asm ds_read_b128 issued one phase before their
// MFMAs, after the barrier. Phase: [stage][vm][BAR][lgkm0(prev reads)][SCHED]
// [issue next reads][SCHED][setprio 16 MFMA].
// ---------------------------------------------------------------------------
#define GL16(g, l) __builtin_amdgcn_global_load_lds( \
    (const __attribute__((address_space(1))) void*)(g), \
    (__attribute__((address_space(3))) void*)(l), 16, 0, 0)

#define DSR(dst, addr, IMM) \
    asm volatile("ds_read_b128 %0, %1 offset:" IMM : "=v"(dst) : "v"(addr))

#define BAR()   __builtin_amdgcn_s_barrier()
#define LGKM0() asm volatile("s_waitcnt lgkmcnt(0)" ::: )
#define SCHED() __builtin_amdgcn_sched_barrier(0)

__global__ __launch_bounds__(512, 2) void gemm256(
    const __bf16* __restrict__ Xb,   // [M][K]
    const __bf16* __restrict__ Wb,   // [N][K]
    const float*  __restrict__ mid,  // [M][16]
    const float*  __restrict__ Bl,   // [N][16]
    float* __restrict__ out,         // [M][N]
    int M, int N, int K)
{
    __shared__ __bf16 As[4][256 * 32];   // 4 x 16 KiB
    __shared__ __bf16 Bs[4][256 * 32];   // 4 x 16 KiB  -> 128 KiB total

    const int NT = K >> 5;               // BK = 32

    int nbx = N >> 8, nby = M >> 8, nwg = nbx * nby;
    int bid = blockIdx.x, swz = bid;
    if ((nwg & 7) == 0) { int cpx = nwg >> 3; swz = (bid & 7) * cpx + (bid >> 3); }
    int by = swz / nbx, bx = swz % nbx;
    int m0 = by << 8, n0 = bx << 8;

    int tid = threadIdx.x;
    int lane = tid & 63;
    int w = tid >> 6;            // wave 0..7
    int wm = w >> 2, wn = w & 3; // 2 x 4 wave grid; wave tile = 128 x 64

    // ---- staging source (pre-swizzled global chunk so linear LDS dest works)
    int q0 = tid >> 2;                       // row within 128-row issue
    int c0 = tid & 3;                        // LDS chunk slot this lane fills
    int csrc = c0 ^ ((q0 >> 1) & 3);         // inverse-swizzled source chunk
    const __bf16* sA0 = Xb + (size_t)(m0 + q0) * K + csrc * 8;
    const __bf16* sA1 = sA0 + (size_t)128 * K;
    const __bf16* sB0 = Wb + (size_t)(n0 + q0) * K + csrc * 8;
    const __bf16* sB1 = sB0 + (size_t)128 * K;
    unsigned ldsw = (unsigned)w * 1024;      // wave-uniform LDS byte base

    // ---- swizzled ds_read byte offsets (chunk ^ f(row); f(row)=((row>>1)&3))
    int chunkSwz = (lane >> 4) ^ ((lane >> 1) & 3);
    unsigned aoff = (unsigned)((wm * 128 + (lane & 15)) * 64 + chunkSwz * 16);
    unsigned boff = (unsigned)((wn * 64  + (lane & 15)) * 64 + chunkSwz * 16);

    // 32-bit LDS addresses for inline-asm ds_read
    unsigned a_addr = (unsigned)(size_t)(__attribute__((address_space(3))) __bf16*)&As[0][0] + aoff;
    unsigned b_addr = (unsigned)(size_t)(__attribute__((address_space(3))) __bf16*)&Bs[0][0] + boff;

#define STAGE_A(t, b) do { size_t ko = (size_t)(t) * 32; \
    GL16(sA0 + ko, (char*)As[b] + ldsw); \
    GL16(sA1 + ko, (char*)As[b] + 8192 + ldsw); } while (0)
#define STAGE_B(t, b) do { size_t ko = (size_t)(t) * 32; \
    GL16(sB0 + ko, (char*)Bs[b] + ldsw); \
    GL16(sB1 + ko, (char*)Bs[b] + 8192 + ldsw); } while (0)

    // ---- acc init = LoRA contribution: mfma([mid|0], [2*Bl|0]) over K=32 ----
    f32x4 acc[8][4];
    {
        int kh = lane >> 4;  // 0..3; k-halves 0,1 hold rank-16 data, 2,3 zero
        bf16x8 bI[4];
#pragma unroll
        for (int j = 0; j < 4; ++j) {
            bf16x8 v = {};
            if (kh < 2) {
                int col = n0 + wn * 64 + j * 16 + (lane & 15);
                const f32x4* p = (const f32x4*)(Bl + (size_t)col * 16 + kh * 8);
                f32x4 v0 = p[0], v1 = p[1];
                v[0] = (__bf16)(2.0f * v0[0]); v[1] = (__bf16)(2.0f * v0[1]);
                v[2] = (__bf16)(2.0f * v0[2]); v[3] = (__bf16)(2.0f * v0[3]);
                v[4] = (__bf16)(2.0f * v1[0]); v[5] = (__bf16)(2.0f * v1[1]);
                v[6] = (__bf16)(2.0f * v1[2]); v[7] = (__bf16)(2.0f * v1[3]);
            }
            bI[j] = v;
        }
#pragma unroll
        for (int i = 0; i < 8; ++i) {
            bf16x8 aI = {};
            if (kh < 2) {
                int row = m0 + wm * 128 + i * 16 + (lane & 15);
                const f32x4* p = (const f32x4*)(mid + (size_t)row * 16 + kh * 8);
                f32x4 v0 = p[0], v1 = p[1];
                aI[0] = (__bf16)v0[0]; aI[1] = (__bf16)v0[1];
                aI[2] = (__bf16)v0[2]; aI[3] = (__bf16)v0[3];
                aI[4] = (__bf16)v1[0]; aI[5] = (__bf16)v1[1];
                aI[6] = (__bf16)v1[2]; aI[7] = (__bf16)v1[3];
            }
            f32x4 z = {0.f, 0.f, 0.f, 0.f};
#pragma unroll
            for (int j = 0; j < 4; ++j)
                acc[i][j] = __builtin_amdgcn_mfma_f32_16x16x32_bf16(aI, bI[j], z, 0, 0, 0);
        }
    }

    // ---- prologue: stage slabs 0,1; certify slab 0; read slab-0 frags ----
    STAGE_A(0, 0); STAGE_B(0, 0);
    STAGE_A(1, 1); STAGE_B(1, 1);
    asm volatile("s_waitcnt vmcnt(4)" ::: "memory");  // slab 0 landed (own)
    BAR();                                            // publish to all waves

    bf16x8 axf0, axf1, axf2, axf3, bxf0, bxf1, bxf2, bxf3;
    bf16x8 ayf0, ayf1, ayf2, ayf3, byf0, byf1, byf2, byf3;
    bf16x8 ax4, ax5, ax6, ax7, ay4, ay5, ay6, ay7;

    DSR(axf0, a_addr, "0");    DSR(axf1, a_addr, "1024");
    DSR(axf2, a_addr, "2048"); DSR(axf3, a_addr, "3072");
    DSR(bxf0, b_addr, "0");    DSR(bxf1, b_addr, "1024");
    DSR(bxf2, b_addr, "2048"); DSR(bxf3, b_addr, "3072");

    // ---- main K loop: 2 slabs / iter, 4 phases ----
    for (int t = 0; t < NT; t += 2) {
        unsigned aT0 = a_addr + ((unsigned)(t & 3) << 14);
        unsigned aT1 = a_addr + ((unsigned)((t + 1) & 3) << 14);
        unsigned bT1 = b_addr + ((unsigned)((t + 1) & 3) << 14);
        unsigned aT2 = a_addr + ((unsigned)((t + 2) & 3) << 14);
        unsigned bT2 = b_addr + ((unsigned)((t + 2) & 3) << 14);
        bool p2 = (t + 2) < NT;
        bool p3 = (t + 3) < NT;

        // ===== PhA(t): MFMA acc[0..3] = axf*bxf; read ax4-7 (slab t) =====
        if (p2) STAGE_A(t + 2, (t + 2) & 3);
        BAR();
        LGKM0();          // certify axf/bxf (drained under previous churn)
        SCHED();
        DSR(ax4, aT0, "4096"); DSR(ax5, aT0, "5120");
        DSR(ax6, aT0, "6144"); DSR(ax7, aT0, "7168");
        SCHED();
        __builtin_amdgcn_s_setprio(1);
        acc[0][0] = __builtin_amdgcn_mfma_f32_16x16x32_bf16(axf0, bxf0, acc[0][0], 0, 0, 0);
        acc[0][1] = __builtin_amdgcn_mfma_f32_16x16x32_bf16(axf0, bxf1, acc[0][1], 0, 0, 0);
        acc[0][2] = __builtin_amdgcn_mfma_f32_16x16x32_bf16(axf0, bxf2, acc[0][2], 0, 0, 0);
        acc[0][3] = __builtin_amdgcn_mfma_f32_16x16x32_bf16(axf0, bxf3, acc[0][3], 0, 0, 0);
        acc[1][0] = __builtin_amdgcn_mfma_f32_16x16x32_bf16(axf1, bxf0, acc[1][0], 0, 0, 0);
        acc[1][1] = __builtin_amdgcn_mfma_f32_16x16x32_bf16(axf1, bxf1, acc[1][1], 0, 0, 0);
        acc[1][2] = __builtin_amdgcn_mfma_f32_16x16x32_bf16(axf1, bxf2, acc[1][2], 0, 0, 0);
        acc[1][3] = __builtin_amdgcn_mfma_f32_16x16x32_bf16(axf1, bxf3, acc[1][3], 0, 0, 0);
        acc[2][0] = __builtin_amdgcn_mfma_f32_16x16x32_bf16(axf2, bxf0, acc[2][0], 0, 0, 0);
        acc[2][1] = __builtin_amdgcn_mfma_f32_16x16x32_bf16(axf2, bxf1, acc[2][1], 0, 0, 0);
        acc[2][2] = __builtin_amdgcn_mfma_f32_16x16x32_bf16(axf2, bxf2, acc[2][2], 0, 0, 0);
        acc[2][3] = __builtin_amdgcn_mfma_f32_16x16x32_bf16(axf2, bxf3, acc[2][3], 0, 0, 0);
        acc[3][0] = __builtin_amdgcn_mfma_f32_16x16x32_bf16(axf3, bxf0, acc[3][0], 0, 0, 0);
        acc[3][1] = __builtin_amdgcn_mfma_f32_16x16x32_bf16(axf3, bxf1, acc[3][1], 0, 0, 0);
        acc[3][2] = __builtin_amdgcn_mfma_f32_16x16x32_bf16(axf3, bxf2, acc[3][2], 0, 0, 0);
        acc[3][3] = __builtin_amdgcn_mfma_f32_16x16x32_bf16(axf3, bxf3, acc[3][3], 0, 0, 0);
        __builtin_amdgcn_s_setprio(0);

        // ===== PhB(t): MFMA acc[4..7] = ax4-7*bxf; read slab t+1 frags =====
        if (p2) {
            STAGE_B(t + 2, (t + 2) & 3);
            asm volatile("s_waitcnt vmcnt(4)" ::: "memory");  // slab t+1 landed
        } else {
            asm volatile("s_waitcnt vmcnt(0)" ::: "memory");
        }
        BAR();
        LGKM0();          // certify ax4-7
        SCHED();
        DSR(ayf0, aT1, "0");    DSR(ayf1, aT1, "1024");
        DSR(ayf2, aT1, "2048"); DSR(ayf3, aT1, "3072");
        DSR(byf0, bT1, "0");    DSR(byf1, bT1, "1024");
        DSR(byf2, bT1, "2048"); DSR(byf3, bT1, "3072");
        SCHED();
        __builtin_amdgcn_s_setprio(1);
        acc[4][0] = __builtin_amdgcn_mfma_f32_16x16x32_bf16(ax4, bxf0, acc[4][0], 0, 0, 0);
        acc[4][1] = __builtin_amdgcn_mfma_f32_16x16x32_bf16(ax4, bxf1, acc[4][1], 0, 0, 0);
        acc[4][2] = __builtin_amdgcn_mfma_f32_16x16x32_bf16(ax4, bxf2, acc[4][2], 0, 0, 0);
        acc[4][3] = __builtin_amdgcn_mfma_f32_16x16x32_bf16(ax4, bxf3, acc[4][3], 0, 0, 0);
        acc[5][0] = __builtin_amdgcn_mfma_f32_16x16x32_bf16(ax5, bxf0, acc[5][0], 0, 0, 0);
        acc[5][1] = __builtin_amdgcn_mfma_f32_16x16x32_bf16(ax5, bxf1, acc[5][1], 0, 0, 0);
        acc[5][2] = __builtin_amdgcn_mfma_f32_16x16x32_bf16(ax5, bxf2, acc[5][2], 0, 0, 0);
        acc[5][3] = __builtin_amdgcn_mfma_f32_16x16x32_bf16(ax5, bxf3, acc[5][3], 0, 0, 0);
        acc[6][0] = __builtin_amdgcn_mfma_f32_16x16x32_bf16(ax6, bxf0, acc[6][0], 0, 0, 0);
        acc[6][1] = __builtin_amdgcn_mfma_f32_16x16x32_bf16(ax6, bxf1, acc[6][1], 0, 0, 0);
        acc[6][2] = __builtin_amdgcn_mfma_f32_16x16x32_bf16(ax6, bxf2, acc[6][2], 0, 0, 0);
        acc[6][3] = __builtin_amdgcn_mfma_f32_16x16x32_bf16(ax6, bxf3, acc[6][3], 0, 0, 0);
        acc[7][0] = __builtin_amdgcn_mfma_f32_16x16x32_bf16(ax7, bxf0, acc[7][0], 0, 0, 0);
        acc[7][1] = __builtin_amdgcn_mfma_f32_16x16x32_bf16(ax7, bxf1, acc[7][1], 0, 0, 0);
        acc[7][2] = __builtin_amdgcn_mfma_f32_16x16x32_bf16(ax7, bxf2, acc[7][2], 0, 0, 0);
        acc[7][3] = __builtin_amdgcn_mfma_f32_16x16x32_bf16(ax7, bxf3, acc[7][3], 0, 0, 0);
        __builtin_amdgcn_s_setprio(0);

        // ===== PhA(t+1): MFMA acc[0..3] = ayf*byf; read ay4-7 (slab t+1) ====
        if (p3) STAGE_A(t + 3, (t + 3) & 3);
        BAR();
        LGKM0();          // certify ayf/byf
        SCHED();
        DSR(ay4, aT1, "4096"); DSR(ay5, aT1, "5120");
        DSR(ay6, aT1, "6144"); DSR(ay7, aT1, "7168");
        SCHED();
        __builtin_amdgcn_s_setprio(1);
        acc[0][0] = __builtin_amdgcn_mfma_f32_16x16x32_bf16(ayf0, byf0, acc[0][0], 0, 0, 0);
        acc[0][1] = __builtin_amdgcn_mfma_f32_16x16x32_bf16(ayf0, byf1, acc[0][1], 0, 0, 0);
        acc[0][2] = __builtin_amdgcn_mfma_f32_16x16x32_bf16(ayf0, byf2, acc[0][2], 0, 0, 0);
        acc[0][3] = __builtin_amdgcn_mfma_f32_16x16x32_bf16(ayf0, byf3, acc[0][3], 0, 0, 0);
        acc[1][0] = __builtin_amdgcn_mfma_f32_16x16x32_bf16(ayf1, byf0, acc[1][0], 0, 0, 0);
        acc[1][1] = __builtin_amdgcn_mfma_f32_16x16x32_bf16(ayf1, byf1, acc[1][1], 0, 0, 0);
        acc[1][2] = __builtin_amdgcn_mfma_f32_16x16x32_bf16(ayf1, byf2, acc[1][2], 0, 0, 0);
        acc[1][3] = __builtin_amdgcn_mfma_f32_16x16x32_bf16(ayf1, byf3, acc[1][3], 0, 0, 0);
        acc[2][0] = __builtin_amdgcn_mfma_f32_16x16x32_bf16(ayf2, byf0, acc[2][0], 0, 0, 0);
        acc[2][1] = __builtin_amdgcn_mfma_f32_16x16x32_bf16(ayf2, byf1, acc[2][1], 0, 0, 0);
        acc[2][2] = __builtin_amdgcn_mfma_f32_16x16x32_bf16(ayf2, byf2, acc[2][2], 0, 0, 0);
        acc[2][3] = __builtin_amdgcn_mfma_f32_16x16x32_bf16(ayf2, byf3, acc[2][3], 0, 0, 0);
        acc[3][0] = __builtin_amdgcn_mfma_f32_16x16x32_bf16(ayf3, byf0, acc[3][0], 0, 0, 0);
        acc[3][1] = __builtin_amdgcn_mfma_f32_16x16x32_bf16(ayf3, byf1, acc[3][1], 0, 0, 0);
        acc[3][2] = __builtin_amdgcn_mfma_f32_16x16x32_bf16(ayf3, byf2, acc[3][2], 0, 0, 0);
        acc[3][3] = __builtin_amdgcn_mfma_f32_16x16x32_bf16(ayf3, byf3, acc[3][3], 0, 0, 0);
        __builtin_amdgcn_s_setprio(0);

        // ===== PhB(t+1): MFMA acc[4..7] = ay4-7*byf; refill slab t+2 frags ==
        if (p3) {
            STAGE_B(t + 3, (t + 3) & 3);
            asm volatile("s_waitcnt vmcnt(4)" ::: "memory");  // slab t+2 landed
        } else {
            asm volatile("s_waitcnt vmcnt(0)" ::: "memory");
        }
        BAR();
        LGKM0();          // certify ay4-7
        SCHED();
        if (p2) {
            DSR(axf0, aT2, "0");    DSR(axf1, aT2, "1024");
            DSR(axf2, aT2, "2048"); DSR(axf3, aT2, "3072");
            DSR(bxf0, bT2, "0");    DSR(bxf1, bT2, "1024");
            DSR(bxf2, bT2, "2048"); DSR(bxf3, bT2, "3072");
        }
        SCHED();
        __builtin_amdgcn_s_setprio(1);
        acc[4][0] = __builtin_amdgcn_mfma_f32_16x16x32_bf16(ay4, byf0, acc[4][0], 0, 0, 0);
        acc[4][1] = __builtin_amdgcn_mfma_f32_16x16x32_bf16(ay4, byf1, acc[4][1], 0, 0, 0);
        acc[4][2] = __builtin_amdgcn_mfma_f32_16x16x32_bf16(ay4, byf2, acc[4][2], 0, 0, 0);
        acc[4][3] = __builtin_amdgcn_mfma_f32_16x16x32_bf16(ay4, byf3, acc[4][3], 0, 0, 0);
        acc[5][0] = __builtin_amdgcn_mfma_f32_16x16x32_bf16(ay5, byf0, acc[5][0], 0, 0, 0);
        acc[5][1] = __builtin_amdgcn_mfma_f32_16x16x32_bf16(ay5, byf1, acc[5][1], 0, 0, 0);
        acc[5][2] = __builtin_amdgcn_mfma_f32_16x16x32_bf16(ay5, byf2, acc[5][2], 0, 0, 0);
        acc[5][3] = __builtin_amdgcn_mfma_f32_16x16x32_bf16(ay5, byf3, acc[5][3], 0, 0, 0);
        acc[6][0] = __builtin_amdgcn_mfma_f32_16x16x32_bf16(ay6, byf0, acc[6][0], 0, 0, 0);
        acc[6][1] = __builtin_amdgcn_mfma_f32_16x16x32_bf16(ay6, byf1, acc[6][1], 0, 0, 0);
        acc[6][2] = __builtin_amdgcn_mfma_f32_16x16x32_bf16(ay6, byf2, acc[6][2], 0, 0, 0);
        acc[6][3] = __builtin_amdgcn_mfma_f32_16x16x32_bf16(ay6, byf3, acc[6][3], 0, 0, 0);
        acc[7][0] = __builtin_amdgcn_mfma_f32_16x16x32_bf16(ay7, byf0, acc[7][0], 0, 0, 0);
        acc[7][1] = __builtin_amdgcn_mfma_f32_16x16x32_bf16(ay7, byf1, acc[7][1], 0, 0, 0);
        acc[7][2] = __builtin_amdgcn_mfma_f32_16x16x32_bf16(ay7, byf2, acc[7][2], 0, 0, 0);
        acc[7][3] = __builtin_amdgcn_mfma_f32_16x16x32_bf16(ay7, byf3, acc[7][3], 0, 0, 0);
        __builtin_amdgcn_s_setprio(0);
    }

    // ---- epilogue: pure f32 stores (LoRA already in acc) ----
#pragma unroll
    for (int i = 0; i < 8; ++i) {
        int rbase = m0 + wm * 128 + i * 16 + ((lane >> 4) << 2);
#pragma unroll
        for (int q = 0; q < 4; ++q) {
            float* orow = out + (size_t)(rbase + q) * N;
            int colb = n0 + wn * 64 + (lane & 15);
            orow[colb]      = acc[i][0][q];
            orow[colb + 16] = acc[i][1][q];
            orow[colb + 32] = acc[i][2][q];
            orow[colb + 48] = acc[i][3][q];
        }
    }
}

// ---------------------------------------------------------------------------
// Fallback fp32 GEMM (used only if workspace too small for bf16 buffers)
// ---------------------------------------------------------------------------
__global__ __launch_bounds__(256) void gemm_fb(
    const float* __restrict__ X, const float* __restrict__ W,
    const float* __restrict__ mid, const float* __restrict__ Bl,
    float* __restrict__ out, int M, int N, int K)
{
    __shared__ float As[64][16];
    __shared__ float Bs[64][16];
    int nbx = N / 64;
    int bx = blockIdx.x % nbx, by = blockIdx.x / nbx;
    int m0 = by * 64, n0 = bx * 64;
    int tid = threadIdx.x;
    int tr = tid >> 4, tc = tid & 15;

    float acc[4][4] = {};
    for (int kt = 0; kt < K; kt += 16) {
#pragma unroll
        for (int s = 0; s < 4; ++s) {
            int c = s * 256 + tid;
            int row = c >> 4, kk = c & 15;
            As[row][kk] = X[(size_t)(m0 + row) * K + kt + kk];
            Bs[row][kk] = W[(size_t)(n0 + row) * K + kt + kk];
        }
        __syncthreads();
#pragma unroll
        for (int kk = 0; kk < 16; ++kk) {
            float av[4], bv[4];
#pragma unroll
            for (int i = 0; i < 4; ++i) { av[i] = As[tr*4+i][kk]; bv[i] = Bs[tc*4+i][kk]; }
#pragma unroll
            for (int i = 0; i < 4; ++i)
#pragma unroll
                for (int j = 0; j < 4; ++j) acc[i][j] += av[i] * bv[j];
        }
        __syncthreads();
    }
#pragma unroll
    for (int i = 0; i < 4; ++i) {
        int row = m0 + tr * 4 + i;
#pragma unroll
        for (int j = 0; j < 4; ++j) {
            int col = n0 + tc * 4 + j;
            float s = 0.f;
#pragma unroll
            for (int r = 0; r < 16; ++r)
                s += mid[(size_t)row * 16 + r] * Bl[(size_t)col * 16 + r];
            out[(size_t)row * N + col] = acc[i][j] + 2.0f * s;
        }
    }
}

// ---------------------------------------------------------------------------
extern "C" void kernel_launch(void* const* d_in, const int* in_sizes, int n_in,
                              void* d_out, int out_size, void* d_ws, size_t ws_size,
                              hipStream_t stream)
{
    const float* x   = (const float*)d_in[0];
    const float* Wf  = (const float*)d_in[1];
    const float* A   = (const float*)d_in[2];
    const float* Bl  = (const float*)d_in[3];
    float* out = (float*)d_out;

    int D = in_sizes[2] / 16;            // A is [16, D]
    int O = in_sizes[3] / 16;            // B is [O, 16]
    long M = (long)in_sizes[0] / D;      // x is [M, D]
    int K = D, N = O;

    size_t xb_bytes  = (size_t)M * K * 2;
    size_t wb_bytes  = (size_t)N * K * 2;
    size_t mid_bytes = (size_t)M * 16 * 4;

    bool shapes_ok = (M % 256 == 0) && (N % 256 == 0) && (K % 2048 == 0)
                     && (K / 32 >= 8);

    int midBlocks = (int)((M + 3) / 4);

    if (shapes_ok && ws_size >= xb_bytes + wb_bytes + mid_bytes) {
        __bf16* Xb  = (__bf16*)d_ws;
        __bf16* Wbb = (__bf16*)((char*)d_ws + xb_bytes);
        float*  mid = (float*)((char*)d_ws + xb_bytes + wb_bytes);

        const int wBlocks = 1024;
        long nW8 = (long)N * K / 8;
        preproc<<<wBlocks + midBlocks, 256, 0, stream>>>(
            x, A, Wf, mid, Xb, Wbb, K, (int)M, nW8, wBlocks);
        int nwg = (int)(M / 256) * (N / 256);
        gemm256<<<nwg, 512, 0, stream>>>(Xb, Wbb, mid, Bl, out, (int)M, N, K);
    } else {
        float* mid = (float*)d_ws;
        mid_only<<<midBlocks, 256, 0, stream>>>(x, A, mid, K, (int)M);
        int nwg = (int)(M / 64) * (N / 64);
        gemm_fb<<<nwg, 256, 0, stream>>>(x, Wf, mid, Bl, out, (int)M, N, K);
    }
}